// Round 8
// baseline (151.848 us; speedup 1.0000x reference)
//
#include <hip/hip_runtime.h>

#define GRID_S 7
#define NUM_CLASSES 80
#define D_DIM 90
#define LAMBDA_COORD 5.0f
#define LAMBDA_NOOBJ 0.5f
#define EPS_IOU 1e-6f
#define EPS_SQRT 1e-6f

__device__ __forceinline__ float iou_img(float cx1, float cy1, float w1, float h1,
                                         float cx2, float cy2, float w2, float h2) {
    float ixmin = fmaxf(cx1 - w1 * 0.5f, cx2 - w2 * 0.5f);
    float iymin = fmaxf(cy1 - h1 * 0.5f, cy2 - h2 * 0.5f);
    float ixmax = fminf(cx1 + w1 * 0.5f, cx2 + w2 * 0.5f);
    float iymax = fminf(cy1 + h1 * 0.5f, cy2 + h2 * 0.5f);
    float iw = fmaxf(ixmax - ixmin, 0.0f);
    float ih = fmaxf(iymax - iymin, 0.0f);
    float inter = iw * ih;
    float uni = w1 * h1 + w2 * h2 - inter;
    return inter / (uni + EPS_IOU);
}

// part layout: per block, 4 floats: [n_obj, coord, conf, cls]
// Obj-gated: class data (80/90 of bytes) only read for obj cells (~25%).
// Phase 2 spreads each obj cell across the block's 4 waves (class quarters),
// so all 4 waves issue gather loads -> 4x the latency-hiding of R7.
__global__ __launch_bounds__(256) void yolo_gated_kernel(
        const float* __restrict__ pred, const float* __restrict__ targ,
        float* __restrict__ part, int ncells) {
    const int tid = threadIdx.x;
    const int cell = blockIdx.x * 256 + tid;

    __shared__ int s_list[256];
    __shared__ int s_count;
    if (tid == 0) s_count = 0;
    __syncthreads();

    float v_obj = 0.0f, v_coord = 0.0f, v_conf = 0.0f, v_cls = 0.0f;

    // ---- phase 1: flag + noobj-conf (3 float2 loads per cell) ----
    bool obj = false;
    if (cell < ncells) {
        const float2* t2 = (const float2*)(targ + (size_t)cell * D_DIM);
        const float2* p2 = (const float2*)(pred + (size_t)cell * D_DIM);
        float2 tf = t2[2];   // targ[4] (obj flag), targ[5]
        float2 pa = p2[2];   // pred[4] (b1 conf), pred[5]
        float2 pb = p2[4];   // pred[8], pred[9] (b2 conf)
        obj = (tf.x == 1.0f);
        if (obj) {
            v_obj = 1.0f;
        } else {
            v_conf = LAMBDA_NOOBJ * (pa.x * pa.x + pb.y * pb.y);
        }
    }

    // ---- compact obj cells into LDS list ----
    if (obj) {
        int idx = atomicAdd(&s_count, 1);
        s_list[idx] = cell;
    }
    __syncthreads();
    const int n = s_count;

    // ---- phase 2: entry k -> lane k of ALL 4 waves; wave `sub` handles class
    //      float2 range [5+10*sub, 15+10*sub); sub 0 also does box/conf ----
    const int lane6 = tid & 63;
    const int sub = tid >> 6;
    for (int k0 = 0; k0 < n; k0 += 64) {
        const int k = k0 + lane6;
        if (k < n) {
            const int c = s_list[k];
            const float2* p2 = (const float2*)(pred + (size_t)c * D_DIM);
            const float2* t2 = (const float2*)(targ + (size_t)c * D_DIM);

            // class quarter: 10 float2 from each array, independent loads
            float cls0 = 0.0f, cls1 = 0.0f;
            const int s2 = 5 + 10 * sub;
            #pragma unroll
            for (int j = 0; j < 10; ++j) {
                float2 pc = p2[s2 + j];
                float2 tc = t2[s2 + j];
                float dx = pc.x - tc.x;
                float dy = pc.y - tc.y;
                cls0 = fmaf(dx, dx, cls0);
                cls1 = fmaf(dy, dy, cls1);
            }
            v_cls += (cls0 + cls1) * (1.0f / (float)NUM_CLASSES);

            if (sub == 0) {
                float2 pq0 = p2[0], pq1 = p2[1], pq2 = p2[2], pq3 = p2[3], pq4 = p2[4];
                float2 tq0 = t2[0], tq1 = t2[1];

                float b1x = pq0.x, b1y = pq0.y, b1w = pq1.x, b1h = pq1.y, b1c = pq2.x;
                float b2x = pq2.y, b2y = pq3.x, b2w = pq3.y, b2h = pq4.x, b2c = pq4.y;
                float tbx = tq0.x, tby = tq0.y, tbw = tq1.x, tbh = tq1.y;

                const int gxy = c % (GRID_S * GRID_S);
                const float gy = (float)(gxy / GRID_S);
                const float gx = (float)(gxy % GRID_S);
                const float invS = 1.0f / (float)GRID_S;
                float c1x = (gx + b1x) * invS, c1y = (gy + b1y) * invS;
                float c2x = (gx + b2x) * invS, c2y = (gy + b2y) * invS;
                float ctx = (gx + tbx) * invS, cty = (gy + tby) * invS;

                float iou1 = iou_img(c1x, c1y, b1w, b1h, ctx, cty, tbw, tbh);
                float iou2 = iou_img(c2x, c2y, b2w, b2h, ctx, cty, tbw, tbh);
                bool resp1 = iou1 > iou2;

                float bx = resp1 ? b1x : b2x;
                float by = resp1 ? b1y : b2y;
                float bw = resp1 ? b1w : b2w;
                float bh = resp1 ? b1h : b2h;
                float bc = resp1 ? b1c : b2c;

                float ddx = bx - tbx, ddy = by - tby;
                float dxy2 = ddx * ddx + ddy * ddy;
                float swpw = sqrtf(fmaxf(bw, EPS_SQRT));
                float swph = sqrtf(fmaxf(bh, EPS_SQRT));
                float swtw = sqrtf(fmaxf(tbw, EPS_SQRT));
                float swth = sqrtf(fmaxf(tbh, EPS_SQRT));
                float dw = swpw - swtw, dh = swph - swth;
                float dwh2 = dw * dw + dh * dh;

                v_coord += 0.5f * dxy2 + 0.5f * dwh2;
                float dco = bc - 1.0f;
                v_conf += dco * dco;
            }
        }
    }

    // ---- block reduction ----
    #pragma unroll
    for (int off = 32; off > 0; off >>= 1) {
        v_obj   += __shfl_down(v_obj, off, 64);
        v_coord += __shfl_down(v_coord, off, 64);
        v_conf  += __shfl_down(v_conf, off, 64);
        v_cls   += __shfl_down(v_cls, off, 64);
    }
    __shared__ float red[4][4];
    const int lane = tid & 63;
    const int wid = tid >> 6;
    if (lane == 0) {
        red[wid][0] = v_obj;
        red[wid][1] = v_coord;
        red[wid][2] = v_conf;
        red[wid][3] = v_cls;
    }
    __syncthreads();
    if (tid < 4) {
        float s = red[0][tid] + red[1][tid] + red[2][tid] + red[3][tid];
        part[(size_t)blockIdx.x * 4 + tid] = s;
    }
}

__global__ __launch_bounds__(1024) void yolo_final_kernel(
        const float* __restrict__ part, float* __restrict__ out,
        int nblocks, int ncells) {
    const int tid = threadIdx.x;
    float a0 = 0.0f, a1 = 0.0f, a2 = 0.0f, a3 = 0.0f;
    const float4* p4 = (const float4*)part;
    for (int b = tid; b < nblocks; b += 1024) {
        float4 v = p4[b];
        a0 += v.x; a1 += v.y; a2 += v.z; a3 += v.w;
    }
    #pragma unroll
    for (int off = 32; off > 0; off >>= 1) {
        a0 += __shfl_down(a0, off, 64);
        a1 += __shfl_down(a1, off, 64);
        a2 += __shfl_down(a2, off, 64);
        a3 += __shfl_down(a3, off, 64);
    }
    __shared__ float red[16][4];
    const int wid = tid >> 6;
    if ((tid & 63) == 0) {
        red[wid][0] = a0; red[wid][1] = a1; red[wid][2] = a2; red[wid][3] = a3;
    }
    __syncthreads();
    if (tid == 0) {
        float n_obj = 0.0f, coord = 0.0f, conf = 0.0f, cls = 0.0f;
        #pragma unroll
        for (int w = 0; w < 16; ++w) {
            n_obj += red[w][0]; coord += red[w][1];
            conf  += red[w][2]; cls   += red[w][3];
        }
        float n_cells = (float)ncells;
        float conf_count = n_obj + 2.0f * (n_cells - n_obj);
        float denom = fmaxf(n_obj, 1.0f);
        out[0] = LAMBDA_COORD * coord / denom + conf / fmaxf(conf_count, 1.0f) + cls / denom;
    }
}

extern "C" void kernel_launch(void* const* d_in, const int* in_sizes, int n_in,
                              void* d_out, int out_size, void* d_ws, size_t ws_size,
                              hipStream_t stream) {
    const float* pred = (const float*)d_in[0];
    const float* targ = (const float*)d_in[1];
    float* part = (float*)d_ws;
    float* out = (float*)d_out;

    const int ncells = in_sizes[0] / D_DIM;      // B * S * S
    const int nblocks = (ncells + 255) / 256;    // 784 for the bench shape

    yolo_gated_kernel<<<nblocks, 256, 0, stream>>>(pred, targ, part, ncells);
    yolo_final_kernel<<<1, 1024, 0, stream>>>(part, out, nblocks, ncells);
}